// Round 9
// baseline (15.122 us; speedup 1.0000x reference)
//
#include <hip/hip_runtime.h>

#define N_ROWS 16384
#define DIM 512
#define NBLK 512           // 512 blocks x 8 waves x 4 rows = 16384 rows
#define NTHR 512
#define WAVES_PER_BLK (NTHR / 64)
#define ROWS_PER_WAVE 4
#define MAGIC 0x5AC0FFEEu  // != 0x00000000 and != 0xAAAAAAAA (poison)

typedef float f32x4 __attribute__((ext_vector_type(4)));

// Fused grid reduction via slot handshake (R7, 14.95us): flag+data packed in
// one u64, agent-scope relaxed atomics only — no fences (R1 pathology), no
// same-address RMW (R3 pathology). Block 0 polls, reduces, restores slots to
// 0 (self-reinitializing workspace across graph replays).
// R8 change: labels are wave-uniform -> readfirstlane makes the compiler
// prove it and emit scalar s_loads at kernel entry; center addresses form in
// SGPRs and the 8 center vloads issue without waiting on a prior VMEM
// round-trip. Cuts one full load-latency from every wave's critical path.

__global__ __launch_bounds__(NTHR) void centerloss_onepass(
    const float* __restrict__ features,
    const int* __restrict__ labels,
    const float* __restrict__ centers,
    float* __restrict__ out,
    unsigned long long* __restrict__ slots)
{
    const int lane  = threadIdx.x & 63;
    // wave id — provably wave-uniform via readfirstlane
    const int wid   = __builtin_amdgcn_readfirstlane(threadIdx.x >> 6);
    const int gwave = blockIdx.x * WAVES_PER_BLK + wid;
    const int base  = gwave * ROWS_PER_WAVE;      // 4 consecutive rows

    // labels: uniform address -> scalar loads through constant cache,
    // issued at kernel entry (no VMEM dependency for center addresses)
    const int* __restrict__ lab = labels + (size_t)base * 2;
    int cls0 = lab[1];
    int cls1 = lab[3];
    int cls2 = lab[5];
    int cls3 = lab[7];

    // center bases computed from SGPR cls -> vloads issue immediately
    const f32x4* __restrict__ c0 =
        reinterpret_cast<const f32x4*>(centers + (size_t)cls0 * DIM);
    const f32x4* __restrict__ c1 =
        reinterpret_cast<const f32x4*>(centers + (size_t)cls1 * DIM);
    const f32x4* __restrict__ c2 =
        reinterpret_cast<const f32x4*>(centers + (size_t)cls2 * DIM);
    const f32x4* __restrict__ c3 =
        reinterpret_cast<const f32x4*>(centers + (size_t)cls3 * DIM);
    f32x4 ca0 = c0[lane];  f32x4 cb0 = c0[lane + 64];
    f32x4 ca1 = c1[lane];  f32x4 cb1 = c1[lane + 64];
    f32x4 ca2 = c2[lane];  f32x4 cb2 = c2[lane + 64];
    f32x4 ca3 = c3[lane];  f32x4 cb3 = c3[lane + 64];

    // features: streamed once, nontemporal
    const f32x4* __restrict__ f4 =
        reinterpret_cast<const f32x4*>(features + (size_t)base * DIM);
    f32x4 fa0 = __builtin_nontemporal_load(&f4[lane +   0]);
    f32x4 fb0 = __builtin_nontemporal_load(&f4[lane +  64]);
    f32x4 fa1 = __builtin_nontemporal_load(&f4[lane + 128]);
    f32x4 fb1 = __builtin_nontemporal_load(&f4[lane + 192]);
    f32x4 fa2 = __builtin_nontemporal_load(&f4[lane + 256]);
    f32x4 fb2 = __builtin_nontemporal_load(&f4[lane + 320]);
    f32x4 fa3 = __builtin_nontemporal_load(&f4[lane + 384]);
    f32x4 fb3 = __builtin_nontemporal_load(&f4[lane + 448]);

    f32x4 d, vsum;
    d = fa0 - ca0; vsum  = d * d;
    d = fb0 - cb0; vsum += d * d;
    d = fa1 - ca1; vsum += d * d;
    d = fb1 - cb1; vsum += d * d;
    d = fa2 - ca2; vsum += d * d;
    d = fb2 - cb2; vsum += d * d;
    d = fa3 - ca3; vsum += d * d;
    d = fb3 - cb3; vsum += d * d;

    float lsum = vsum.x + vsum.y + vsum.z + vsum.w;

    #pragma unroll
    for (int off = 1; off < 64; off <<= 1)
        lsum += __shfl_xor(lsum, off, 64);

    __shared__ float smem[WAVES_PER_BLK];
    if (lane == 0) smem[wid] = lsum;
    __syncthreads();

    if (threadIdx.x == 0) {
        float b = 0.f;
        #pragma unroll
        for (int w = 0; w < WAVES_PER_BLK; ++w) b += smem[w];
        unsigned long long v =
            ((unsigned long long)__float_as_uint(b) << 32) | (unsigned long long)MAGIC;
        __hip_atomic_store(&slots[blockIdx.x], v,
                           __ATOMIC_RELAXED, __HIP_MEMORY_SCOPE_AGENT);
    }

    if (blockIdx.x != 0) return;

    // ---- block 0: consume all 512 slots (one per thread) ----
    unsigned long long v;
    for (;;) {
        v = __hip_atomic_load(&slots[threadIdx.x],
                              __ATOMIC_RELAXED, __HIP_MEMORY_SCOPE_AGENT);
        if ((unsigned)v == MAGIC) break;
        __builtin_amdgcn_s_sleep(2);
    }
    float p = __uint_as_float((unsigned)(v >> 32));
    // restore slot to 0 for the next graph replay (self-reinit workspace)
    __hip_atomic_store(&slots[threadIdx.x], 0ull,
                       __ATOMIC_RELAXED, __HIP_MEMORY_SCOPE_AGENT);

    #pragma unroll
    for (int off = 1; off < 64; off <<= 1)
        p += __shfl_xor(p, off, 64);

    __shared__ float smem2[WAVES_PER_BLK];
    if (lane == 0) smem2[wid] = p;
    __syncthreads();
    if (threadIdx.x == 0) {
        float t = 0.f;
        #pragma unroll
        for (int w = 0; w < WAVES_PER_BLK; ++w) t += smem2[w];
        out[0] = t / (float)N_ROWS;
    }
}

extern "C" void kernel_launch(void* const* d_in, const int* in_sizes, int n_in,
                              void* d_out, int out_size, void* d_ws, size_t ws_size,
                              hipStream_t stream)
{
    const float* features = (const float*)d_in[0];
    const int*   labels   = (const int*)d_in[1];
    const float* centers  = (const float*)d_in[2];
    float* out = (float*)d_out;
    unsigned long long* slots = (unsigned long long*)d_ws;

    centerloss_onepass<<<NBLK, NTHR, 0, stream>>>(features, labels, centers, out, slots);
}